// Round 4
// baseline (96.956 us; speedup 1.0000x reference)
//
#include <hip/hip_runtime.h>
#include <hip/hip_bf16.h>

// Problem: B=8, N=4096, H=256, F=6
//   Wt[b][n][h] = sum_f osc[f][h][n] * sin(freq_f * t[b] + phase[f][n])
//   out[b][m][n] = sum_h x[b][m][h] * Wt[b][n][h]
//
// R12 = R11 (92.29) + store-relabel epilogue + full-A prologue prefetch.
//   Budget (from R9 cross-check): harness-fixed floor ~65 µs (unconditional
//   256 MiB ws poison @43 + restores + gaps); controllable = build_w (~4)
//   + gemm (~20 vs 11 µs BW roofline).
//   - B-frag n-relabel: column lane15 is fed Wt row n = wn*64+lane15*4+nt
//     -> lane's 4 nt-accumulators are 4 CONSECUTIVE n -> epilogue is
//     8x global_store_dwordx4 nt (4 rows x 256 B contiguous per instr)
//     instead of 32x dword (4 rows x 64 B partial-line). Read-side XOR
//     formula unchanged ((kh*4+quad)^(lane15&7)); only the gload_lds
//     SOURCE chunk becomes (lane&7)^(j*2+(lane>>5)).
//   - A panel (4 k-tiles, 32 VGPR) prefetched entirely in prologue with
//     nontemporal loads (X is stream-once; preserves Wt L2 residency).
//     Per-iter vmem issue is now B-only: vmcnt(4) counts exactly the
//     next B tile; B(it+2) issued right after the post-compute barrier.

#define B_  8
#define N_  4096
#define H_  256

typedef __attribute__((ext_vector_type(8))) short s8v;   // 8 bf16 (A/B frag)
typedef __attribute__((ext_vector_type(4))) float f4v;   // C/D frag / 16B store

#define AS1 __attribute__((address_space(1)))
#define AS3 __attribute__((address_space(3)))
#define GLOAD_LDS16(g, l) \
    __builtin_amdgcn_global_load_lds((const AS1 void*)(g), (AS3 void*)(l), 16, 0, 0)

__global__ __launch_bounds__(256) void build_w(
    const float* __restrict__ osc,     // [6][256][256]  osc[f][h][n]
    const float* __restrict__ t,       // [8][1]
    const float* __restrict__ phase,   // [6][256]       phase[f][n]
    __hip_bfloat16* __restrict__ Wt)   // [8][256][256]  Wt[b][n][h]
{
    const float freqs[6] = {1.f, 2.f, 4.f, 8.f, 7.f, 5.f};
    __shared__ float tr[16 * 68];      // [hlocal][n], stride 68

    const int b  = blockIdx.z;
    const int n0 = blockIdx.y * 64;    // 4 n-tiles
    const int h0 = blockIdx.x * 16;    // 16 h-slices
    const int tid = threadIdx.x;

    const float tb = t[b];
    const int nr = (tid & 15) * 4;
    const int hr = tid >> 4;           // 0..15
    float s[6][4];
#pragma unroll
    for (int f = 0; f < 6; ++f)
#pragma unroll
        for (int j = 0; j < 4; ++j)
            s[f][j] = __sinf(freqs[f] * tb + phase[f * 256 + n0 + nr + j]);

    const int h = h0 + hr;
    float4 acc = make_float4(0.f, 0.f, 0.f, 0.f);
#pragma unroll
    for (int f = 0; f < 6; ++f) {
        float4 o = *(const float4*)&osc[f * 65536 + h * 256 + n0 + nr];
        acc.x += o.x * s[f][0];
        acc.y += o.y * s[f][1];
        acc.z += o.z * s[f][2];
        acc.w += o.w * s[f][3];
    }
    *(float4*)&tr[hr * 68 + nr] = acc;
    __syncthreads();

    const int nw = tid >> 2;           // 0..63
    const int hw = (tid & 3) * 4;      // 0,4,8,12
    float v0 = tr[(hw + 0) * 68 + nw];
    float v1 = tr[(hw + 1) * 68 + nw];
    float v2 = tr[(hw + 2) * 68 + nw];
    float v3 = tr[(hw + 3) * 68 + nw];
    union { __hip_bfloat162 h2[2]; unsigned long long q; } cv;
    cv.h2[0] = __float22bfloat162_rn(make_float2(v0, v1));
    cv.h2[1] = __float22bfloat162_rn(make_float2(v2, v3));
    *(unsigned long long*)(Wt + (size_t)b * 65536 + (size_t)(n0 + nw) * 256 + h0 + hw) = cv.q;
}

#define LDA 72    // As row stride in shorts (144 B, 2-way class, clean — R6)

// BM=64, BN=256, BK=64 x 4 iters. 8 waves: wm in {0,1}, wn in {0..3}.
__global__ __launch_bounds__(512, 4) void gemm(
    const float* __restrict__ X,              // [8][4096][256] fp32
    const __hip_bfloat16* __restrict__ Wt,    // [8][256][256]  bf16 [b][n][h]
    float* __restrict__ out)                  // [8][4096][256] fp32
{
    __shared__ short As[64 * LDA];            //  9.2 KB, reg-staged (fp32->bf16)
    __shared__ short Bs[2][256 * 64];         // 2x32 KB dense, XOR-swizzled content
                                              // total 73 KB -> 2 blocks/CU

    const int b     = blockIdx.y;
    const int mTile = blockIdx.x;             // 0..63

    const int tid    = threadIdx.x;
    const int lane   = tid & 63;
    const int wave   = tid >> 6;              // 0..7
    const int lane15 = lane & 15;
    const int quad   = lane >> 4;             // 0..3
    const int wm     = wave >> 2;             // 0..1
    const int wn     = wave & 3;              // 0..3

    const float* Xb          = X   + (size_t)b * N_ * H_ + (size_t)mTile * 64 * H_;
    const __hip_bfloat16* Wb = Wt  + (size_t)b * H_ * H_;
    float* Ob                = out + (size_t)b * N_ * H_ + (size_t)mTile * 64 * H_;

    // ---- A: full 64x256 panel prefetch (8x float4/thread, nontemporal) ----
    const int arow = tid >> 3;                // 0..63
    const int aseg = (tid & 7) * 8;           // 0,8,..,56
    const float* pa = Xb + (size_t)arow * H_ + aseg;
    f4v av[4][2];
#pragma unroll
    for (int it = 0; it < 4; ++it) {
        av[it][0] = __builtin_nontemporal_load((const f4v*)(pa + it * 64));
        av[it][1] = __builtin_nontemporal_load((const f4v*)(pa + it * 64 + 4));
    }

    // ---- B gload_lds geometry: linear LDS dest, XOR-swizzled SOURCE ----
    //   phys slot: n = wave*32 + j*8 + (lane>>3), chunk c_phys = lane&7
    //   source chunk c_src = c_phys ^ ((n>>2)&7) = (lane&7) ^ (j*2 + (lane>>5))
    const int brow = lane >> 3;               // 0..7
    const int bK   = lane >> 5;               // 0..1
    const __hip_bfloat16* WbRow = Wb + (size_t)(wave * 32 + brow) * H_;

#define ISSUE_B(buf, kt)                                                      \
    do {                                                                      \
        _Pragma("unroll")                                                     \
        for (int j = 0; j < 4; ++j) {                                         \
            const int csrc = (lane & 7) ^ (j * 2 + bK);                       \
            GLOAD_LDS16(WbRow + (size_t)j * 8 * H_ + (kt) * 64 + csrc * 8,    \
                        &Bs[buf][wave * 2048 + j * 512]);                     \
        }                                                                     \
    } while (0)

    f4v acc[2][4] = {};

    // prologue: both B buffers in flight
    ISSUE_B(0, 0);
    ISSUE_B(1, 1);

#pragma unroll
    for (int it = 0; it < 4; ++it) {
        const int p = it & 1;
        // stage A(it): fp32 -> bf16 in-register, one ds_write_b128
        union { __hip_bfloat162 h2[4]; uint4 q; } cv;
        cv.h2[0] = __float22bfloat162_rn(make_float2(av[it][0][0], av[it][0][1]));
        cv.h2[1] = __float22bfloat162_rn(make_float2(av[it][0][2], av[it][0][3]));
        cv.h2[2] = __float22bfloat162_rn(make_float2(av[it][1][0], av[it][1][1]));
        cv.h2[3] = __float22bfloat162_rn(make_float2(av[it][1][2], av[it][1][3]));
        *(uint4*)&As[arow * LDA + aseg] = cv.q;

        // counted vmcnt: outstanding after B(it) = next B tile (4 loads)
        if (it < 3)
            asm volatile("s_waitcnt vmcnt(4) lgkmcnt(0)\n\ts_barrier" ::: "memory");
        else
            asm volatile("s_waitcnt vmcnt(0) lgkmcnt(0)\n\ts_barrier" ::: "memory");

        // compute on As + Bs[p]; B n-relabel: col lane15 <- row wn*64+lane15*4+nt
#pragma unroll
        for (int kh = 0; kh < 2; ++kh) {
            s8v af[2], bf[4];
#pragma unroll
            for (int mt = 0; mt < 2; ++mt)
                af[mt] = *(const s8v*)&As[(wm * 32 + mt * 16 + lane15) * LDA + kh * 32 + quad * 8];
#pragma unroll
            for (int nt = 0; nt < 4; ++nt) {
                const int n  = wn * 64 + lane15 * 4 + nt;
                const int pc = ((kh * 4 + quad) ^ (lane15 & 7)) * 8;  // XOR on read
                bf[nt] = *(const s8v*)&Bs[p][n * 64 + pc];
            }
#pragma unroll
            for (int mt = 0; mt < 2; ++mt)
#pragma unroll
                for (int nt = 0; nt < 4; ++nt)
                    acc[mt][nt] = __builtin_amdgcn_mfma_f32_16x16x32_bf16(
                        af[mt], bf[nt], acc[mt][nt], 0, 0, 0);
        }
        if (it < 3) {
            asm volatile("s_barrier" ::: "memory");  // Bs[p] reads retired
            if (it < 2)
                ISSUE_B(p, it + 2);                  // refill just-freed buffer
        }
    }

    // epilogue: acc[mt][nt][r] holds (row = wm*32+mt*16+quad*4+r,
    //           n = wn*64+lane15*4+nt) -> 16B contiguous per lane,
    //           4 rows x 256 B contiguous per instruction, nontemporal.
#pragma unroll
    for (int mt = 0; mt < 2; ++mt) {
#pragma unroll
        for (int r = 0; r < 4; ++r) {
            const int row = wm * 32 + mt * 16 + quad * 4 + r;
            f4v o = { acc[mt][0][r], acc[mt][1][r], acc[mt][2][r], acc[mt][3][r] };
            __builtin_nontemporal_store(o,
                (f4v*)(Ob + (size_t)row * H_ + wn * 64 + lane15 * 4));
        }
    }
}

extern "C" void kernel_launch(void* const* d_in, const int* in_sizes, int n_in,
                              void* d_out, int out_size, void* d_ws, size_t ws_size,
                              hipStream_t stream) {
    const float* x     = (const float*)d_in[0];   // [8][4096][256]
    const float* t     = (const float*)d_in[1];   // [8][1]
    const float* osc   = (const float*)d_in[2];   // [6][256][256]
    const float* phase = (const float*)d_in[3];   // [6][256]
    __hip_bfloat16* Wt = (__hip_bfloat16*)d_ws;   // ws poison is unconditional -> free
    float* out = (float*)d_out;
    (void)in_sizes; (void)n_in; (void)out_size; (void)ws_size;

    dim3 gw(16, 4, 8);                            // (h-slice, n-tile, b) = 512 blocks
    build_w<<<gw, 256, 0, stream>>>(osc, t, phase, Wt);

    dim3 gg(64, 8);                               // (mTile, b) = 512 blocks
    gemm<<<gg, 512, 0, stream>>>(x, Wt, out);
}

// Round 5
// 91.574 us; speedup vs baseline: 1.0588x; 1.0588x over previous
//
#include <hip/hip_runtime.h>
#include <hip/hip_bf16.h>

// Problem: B=8, N=4096, H=256, F=6
//   Wt[b][n][h] = sum_f osc[f][h][n] * sin(freq_f * t[b] + phase[f][n])
//   out[b][m][n] = sum_h x[b][m][h] * Wt[b][n][h]
//
// R13 = R11 (92.29, best) + store-relabel epilogue ONLY.
//   R12 stacked {relabel + full-A reg prefetch} and regressed (96.96);
//   the A-prefetch (+32 VGPR vs the 128 cap, forced early drain) is the
//   suspect. This round un-stacks: keep R11's A path and B prefetch
//   schedule verbatim, change only the B n-mapping + epilogue:
//   - B-frag col lane15 is fed Wt row n = wn*64 + lane15*4 + nt ->
//     a lane's 4 nt-accumulators are 4 CONSECUTIVE n -> epilogue is
//     8x global_store_dwordx4 (4 rows x 256 B contiguous per instr)
//     instead of 32x dword (4 rows x 64 B partial-line).
//   - Matched swizzle key (verified correct in R12, absmax 0.0625):
//     content[row][c] = logical[row][c ^ ((row>>2)&7)], i.e. source
//     csrc = (lane&7) ^ (j*2 + (lane>>5)); read pc = (kh*4+quad)^(lane15&7).

#define B_  8
#define N_  4096
#define H_  256

typedef __attribute__((ext_vector_type(8))) short s8v;   // 8 bf16 (A/B frag)
typedef __attribute__((ext_vector_type(4))) float f4v;   // C/D frag / 16B store

#define AS1 __attribute__((address_space(1)))
#define AS3 __attribute__((address_space(3)))
#define GLOAD_LDS16(g, l) \
    __builtin_amdgcn_global_load_lds((const AS1 void*)(g), (AS3 void*)(l), 16, 0, 0)

__global__ __launch_bounds__(256) void build_w(
    const float* __restrict__ osc,     // [6][256][256]  osc[f][h][n]
    const float* __restrict__ t,       // [8][1]
    const float* __restrict__ phase,   // [6][256]       phase[f][n]
    __hip_bfloat16* __restrict__ Wt)   // [8][256][256]  Wt[b][n][h]
{
    const float freqs[6] = {1.f, 2.f, 4.f, 8.f, 7.f, 5.f};
    __shared__ float tr[16 * 68];      // [hlocal][n], stride 68

    const int b  = blockIdx.z;
    const int n0 = blockIdx.y * 64;    // 4 n-tiles
    const int h0 = blockIdx.x * 16;    // 16 h-slices
    const int tid = threadIdx.x;

    const float tb = t[b];
    const int nr = (tid & 15) * 4;
    const int hr = tid >> 4;           // 0..15
    float s[6][4];
#pragma unroll
    for (int f = 0; f < 6; ++f)
#pragma unroll
        for (int j = 0; j < 4; ++j)
            s[f][j] = __sinf(freqs[f] * tb + phase[f * 256 + n0 + nr + j]);

    const int h = h0 + hr;
    float4 acc = make_float4(0.f, 0.f, 0.f, 0.f);
#pragma unroll
    for (int f = 0; f < 6; ++f) {
        float4 o = *(const float4*)&osc[f * 65536 + h * 256 + n0 + nr];
        acc.x += o.x * s[f][0];
        acc.y += o.y * s[f][1];
        acc.z += o.z * s[f][2];
        acc.w += o.w * s[f][3];
    }
    *(float4*)&tr[hr * 68 + nr] = acc;
    __syncthreads();

    const int nw = tid >> 2;           // 0..63
    const int hw = (tid & 3) * 4;      // 0,4,8,12
    float v0 = tr[(hw + 0) * 68 + nw];
    float v1 = tr[(hw + 1) * 68 + nw];
    float v2 = tr[(hw + 2) * 68 + nw];
    float v3 = tr[(hw + 3) * 68 + nw];
    union { __hip_bfloat162 h2[2]; unsigned long long q; } cv;
    cv.h2[0] = __float22bfloat162_rn(make_float2(v0, v1));
    cv.h2[1] = __float22bfloat162_rn(make_float2(v2, v3));
    *(unsigned long long*)(Wt + (size_t)b * 65536 + (size_t)(n0 + nw) * 256 + h0 + hw) = cv.q;
}

#define LDA 72    // As row stride in shorts (144 B, 2-way class, clean — R6)

// BM=64, BN=256, BK=64 x 4 iters. 8 waves: wm in {0,1}, wn in {0..3}.
__global__ __launch_bounds__(512, 4) void gemm(
    const float* __restrict__ X,              // [8][4096][256] fp32
    const __hip_bfloat16* __restrict__ Wt,    // [8][256][256]  bf16 [b][n][h]
    float* __restrict__ out)                  // [8][4096][256] fp32
{
    __shared__ short As[64 * LDA];            //  9.2 KB, reg-staged (fp32->bf16)
    __shared__ short Bs[2][256 * 64];         // 2x32 KB dense, XOR-swizzled content
                                              // total 73 KB -> 2 blocks/CU

    const int b     = blockIdx.y;
    const int mTile = blockIdx.x;             // 0..63

    const int tid    = threadIdx.x;
    const int lane   = tid & 63;
    const int wave   = tid >> 6;              // 0..7
    const int lane15 = lane & 15;
    const int quad   = lane >> 4;             // 0..3
    const int wm     = wave >> 2;             // 0..1
    const int wn     = wave & 3;              // 0..3

    const float* Xb          = X   + (size_t)b * N_ * H_ + (size_t)mTile * 64 * H_;
    const __hip_bfloat16* Wb = Wt  + (size_t)b * H_ * H_;
    float* Ob                = out + (size_t)b * N_ * H_ + (size_t)mTile * 64 * H_;

    // A staging: 64 rows x 64 k fp32 -> 8 floats/thread (32 B contig)
    const int arow = tid >> 3;                // 0..63
    const int aseg = (tid & 7) * 8;           // 0,8,..,56
    const float* pa = Xb + (size_t)arow * H_ + aseg;

    // B gload_lds: LINEAR LDS dest; phys row = wave*32 + j*8 + (lane>>3),
    // phys chunk = lane&7. Source reads logical chunk c ^ ((row>>2)&7):
    //   (row>>2)&7 = j*2 + (lane>>5)  ->  csrc = (lane&7) ^ (j*2 + (lane>>5))
    const int brow = lane >> 3;               // 0..7
    const int bK   = lane >> 5;               // 0..1
    const __hip_bfloat16* WbRow = Wb + (size_t)(wave * 32 + brow) * H_;

#define ISSUE_B(buf, kt)                                                      \
    do {                                                                      \
        _Pragma("unroll")                                                     \
        for (int j = 0; j < 4; ++j) {                                         \
            const int csrc = (lane & 7) ^ (j * 2 + bK);                       \
            GLOAD_LDS16(WbRow + (size_t)j * 8 * H_ + (kt) * 64 + csrc * 8,    \
                        &Bs[buf][wave * 2048 + j * 512]);                     \
        }                                                                     \
    } while (0)

    f4v acc[2][4] = {};

    // ---- prologue: B(0) -> Bs[0], A(0) -> regs (R11 schedule, verbatim)
    ISSUE_B(0, 0);
    float4 av[2][2];
    av[0][0] = *(const float4*)(pa + 0);
    av[0][1] = *(const float4*)(pa + 4);

#pragma unroll
    for (int it = 0; it < 4; ++it) {
        const int p = it & 1;
        // stage A(it): fp32 -> bf16 in-register, one ds_write_b128
        union { __hip_bfloat162 h2[4]; uint4 q; } cv;
        cv.h2[0] = __float22bfloat162_rn(make_float2(av[p][0].x, av[p][0].y));
        cv.h2[1] = __float22bfloat162_rn(make_float2(av[p][0].z, av[p][0].w));
        cv.h2[2] = __float22bfloat162_rn(make_float2(av[p][1].x, av[p][1].y));
        cv.h2[3] = __float22bfloat162_rn(make_float2(av[p][1].z, av[p][1].w));
        *(uint4*)&As[arow * LDA + aseg] = cv.q;

        if (it < 3) {
            // issue B(it+1) -> Bs[p^1] and A(it+1) -> regs (stay in flight
            // across the barrier: counted vmcnt, never 0 mid-loop)
            ISSUE_B(p ^ 1, it + 1);
            av[p ^ 1][0] = *(const float4*)(pa + (it + 1) * 64);
            av[p ^ 1][1] = *(const float4*)(pa + (it + 1) * 64 + 4);
            // newest 6 vmem = B(it+1) x4 + A(it+1) x2 -> vmcnt(6) drains B(it)
            asm volatile("s_waitcnt vmcnt(6) lgkmcnt(0)\n\ts_barrier" ::: "memory");
        } else {
            asm volatile("s_waitcnt vmcnt(0) lgkmcnt(0)\n\ts_barrier" ::: "memory");
        }

        // compute on As + Bs[p]; B n-relabel: col lane15 <- row wn*64+lane15*4+nt
#pragma unroll
        for (int kh = 0; kh < 2; ++kh) {
            s8v af[2], bf[4];
#pragma unroll
            for (int mt = 0; mt < 2; ++mt)
                af[mt] = *(const s8v*)&As[(wm * 32 + mt * 16 + lane15) * LDA + kh * 32 + quad * 8];
#pragma unroll
            for (int nt = 0; nt < 4; ++nt) {
                const int n  = wn * 64 + lane15 * 4 + nt;
                // logical chunk kh*4+quad; key (n>>2)&7 = lane15&7 (nt<4, wn*16%8==0)
                const int pc = ((kh * 4 + quad) ^ (lane15 & 7)) * 8;
                bf[nt] = *(const s8v*)&Bs[p][n * 64 + pc];
            }
#pragma unroll
            for (int mt = 0; mt < 2; ++mt)
#pragma unroll
                for (int nt = 0; nt < 4; ++nt)
                    acc[mt][nt] = __builtin_amdgcn_mfma_f32_16x16x32_bf16(
                        af[mt], bf[nt], acc[mt][nt], 0, 0, 0);
        }
        if (it < 3)
            asm volatile("s_barrier" ::: "memory");  // Bs[p] reads retired
    }

    // epilogue: acc[mt][nt][r] holds (row = wm*32+mt*16+quad*4+r,
    //           n = wn*64+lane15*4+nt) -> 16 B contiguous per lane,
    //           4 rows x 256 B contiguous per instruction, nontemporal.
#pragma unroll
    for (int mt = 0; mt < 2; ++mt) {
#pragma unroll
        for (int r = 0; r < 4; ++r) {
            const int row = wm * 32 + mt * 16 + quad * 4 + r;
            f4v o = { acc[mt][0][r], acc[mt][1][r], acc[mt][2][r], acc[mt][3][r] };
            __builtin_nontemporal_store(o,
                (f4v*)(Ob + (size_t)row * H_ + wn * 64 + lane15 * 4));
        }
    }
}

extern "C" void kernel_launch(void* const* d_in, const int* in_sizes, int n_in,
                              void* d_out, int out_size, void* d_ws, size_t ws_size,
                              hipStream_t stream) {
    const float* x     = (const float*)d_in[0];   // [8][4096][256]
    const float* t     = (const float*)d_in[1];   // [8][1]
    const float* osc   = (const float*)d_in[2];   // [6][256][256]
    const float* phase = (const float*)d_in[3];   // [6][256]
    __hip_bfloat16* Wt = (__hip_bfloat16*)d_ws;   // ws poison is unconditional -> free
    float* out = (float*)d_out;
    (void)in_sizes; (void)n_in; (void)out_size; (void)ws_size;

    dim3 gw(16, 4, 8);                            // (h-slice, n-tile, b) = 512 blocks
    build_w<<<gw, 256, 0, stream>>>(osc, t, phase, Wt);

    dim3 gg(64, 8);                               // (mTile, b) = 512 blocks
    gemm<<<gg, 512, 0, stream>>>(x, Wt, out);
}